// Round 1
// baseline (223.561 us; speedup 1.0000x reference)
//
#include <hip/hip_runtime.h>
#include <math.h>

#define H 128
#define HID 512
#define GRID 2048          // score blocks == partial slots
#define PREP_B 16          // prep blocks == u partial slots

struct Ws {
    float sb_part[PREP_B];
    float u_part[PREP_B][H];
    unsigned long long best_part[GRID];   // 8-aligned (offset 64+8192=8256)
    float Z_part[GRID];
    unsigned int done;                    // last-block-done counter (zeroed by prep)
};

__device__ __forceinline__ unsigned int fkey(float f) {
    unsigned int u = __float_as_uint(f);
    return (u & 0x80000000u) ? ~u : (u | 0x80000000u);
}
__device__ __forceinline__ float inv_fkey(unsigned int k) {
    return __uint_as_float((k & 0x80000000u) ? (k ^ 0x80000000u) : ~k);
}

// ---------------- prep: 16 independent blocks, no cross-block deps ------------
// Also zeroes the score kernel's done-counter; kernel-boundary release makes it
// visible to score's agent-scope RMWs (same-stream dispatch ordering).
__global__ __launch_bounds__(256)
void prep_kernel(const float* __restrict__ outp, const float* __restrict__ W1,
                 const float* __restrict__ b1, const float* __restrict__ W2,
                 const float* __restrict__ b2, const int* __restrict__ prev,
                 Ws* __restrict__ ws) {
    __shared__ float phi1_s[32];
    __shared__ float sb_s[8];
    __shared__ float u_s[2][H];
    int t = threadIdx.x;
    if (blockIdx.x == 0 && t == 0) ws->done = 0u;
    int lane = t & 63;
    int c = lane & 31;
    int g = t >> 5;            // half-wave id 0..7, each owns 4 rows
    int kbase = blockIdx.x * 32;
    const float4* vi = (const float4*)(outp + (size_t)prev[0] * H);
    float4 v = vi[c];
    float sb = 0.f;
#pragma unroll
    for (int r = 0; r < 4; ++r) {
        int kl = g * 4 + r;
        int k = kbase + kl;
        float4 w = ((const float4*)(W1 + (size_t)k * H))[c];
        float d = w.x * v.x + w.y * v.y + w.z * v.z + w.w * v.w;
        d += __shfl_xor(d, 16);
        d += __shfl_xor(d, 8);
        d += __shfl_xor(d, 4);
        d += __shfl_xor(d, 2);
        d += __shfl_xor(d, 1);
        if (c == 0) {
            float phi = d + b1[k];
            phi1_s[kl] = phi;
            sb += phi * b2[k];
        }
    }
    if (c == 0) sb_s[g] = sb;
    __syncthreads();
    int h = t & 127;
    int g2 = t >> 7;           // 0..1
    float up = 0.f;
#pragma unroll
    for (int kk = 0; kk < 16; ++kk) {
        int kl = g2 * 16 + kk;
        up += phi1_s[kl] * W2[(size_t)(kbase + kl) * H + h];
    }
    u_s[g2][h] = up;
    __syncthreads();
    if (t < H) ws->u_part[blockIdx.x][t] = u_s[0][t] + u_s[1][t];
    if (t == 0) {
        float s = 0.f;
#pragma unroll
        for (int i = 0; i < 8; ++i) s += sb_s[i];
        ws->sb_part[blockIdx.x] = s;
    }
}

// ---------------- fused streaming + final reduce ------------------------------
// Main loop identical math to the verified 167µs version (bit-identical Z/best
// path). Changes: (1) next-tile adj prefetch rotates the adj HBM latency under
// the current tile's x traffic; (2) the separate 1-block reduce kernel is
// replaced by a last-block-done reduction: each block publishes its partials
// with agent-scope atomic stores (explicit cross-XCD visibility), bumps the
// counter with acq_rel, and the block observing count==GRID-1 folds all 2048
// partials and writes the output.
__global__ __launch_bounds__(256)
void score_kernel(const float4* __restrict__ xv, const float* __restrict__ adj,
                  Ws* __restrict__ ws, float* __restrict__ outp,
                  int n, int ntiles) {
    __shared__ float zs[4];
    __shared__ unsigned long long bs[4];
    __shared__ int lastflag;
    const float inv = 0.04419417382415922f;   // 1/sqrt(512)
    int t = threadIdx.x;
    int lane = t & 63;
    int c = lane & 31;
    int hv = lane >> 5;
    int w = t >> 6;
    // fold the 16 u/sb partials (8 KB, L2-hot broadcast)
    float4 uv = make_float4(0.f, 0.f, 0.f, 0.f);
    float s_b = 0.f;
#pragma unroll
    for (int b = 0; b < PREP_B; ++b) {
        float4 p = ((const float4*)ws->u_part[b])[c];
        uv.x += p.x; uv.y += p.y; uv.z += p.z; uv.w += p.w;
        s_b += ws->sb_part[b];
    }
    float zloc = 0.f;
    float bscore = -3.4e38f;
    int bidx = -1;

    int tile = blockIdx.x;
    // prefetch first tile's adj (8 values, lanes 0..7)
    float av = 0.f;
    if (tile < ntiles) {
        int rb = tile * 32 + w * 8;
        if (lane < 8 && rb + lane < n) av = adj[rb + lane];
    }
    for (; tile < ntiles; tile += GRID) {
        // issue next tile's adj load now; consumed next iteration
        int tnext = tile + GRID;
        float av_next = 0.f;
        if (tnext < ntiles) {
            int rbn = tnext * 32 + w * 8;
            if (lane < 8 && rbn + lane < n) av_next = adj[rbn + lane];
        }
        int rowbase = tile * 32 + w * 8;
        float a4[4];
        float d[4];
        // predicated loads + partial dots (loads grouped, no waitcnt until use)
#pragma unroll
        for (int r = 0; r < 4; ++r) {
            a4[r] = __shfl(av, hv + 2 * r);
            float dd = 0.f;
            if (a4[r] != 0.f) {
                int row = rowbase + hv + 2 * r;
                float4 x = xv[(size_t)row * 32 + c];
                dd = x.x * uv.x + x.y * uv.y + x.z * uv.z + x.w * uv.w;
            }
            d[r] = dd;
        }
        // butterfly reductions, only for live rows (xor<=16 stays in half-wave)
#pragma unroll
        for (int r = 0; r < 4; ++r) {
            if (a4[r] != 0.f) {
                float dd = d[r];
                dd += __shfl_xor(dd, 16);
                dd += __shfl_xor(dd, 8);
                dd += __shfl_xor(dd, 4);
                dd += __shfl_xor(dd, 2);
                dd += __shfl_xor(dd, 1);
                d[r] = dd;
            }
        }
        // tail: lanes c<4 own row r=c
        if (c < 4) {
            int row = rowbase + hv + 2 * c;
            if (row < n) {
                float a = a4[0];
                float dm = d[0];
#pragma unroll
                for (int r = 1; r < 4; ++r) {
                    a  = (c == r) ? a4[r] : a;
                    dm = (c == r) ? d[r] : dm;
                }
                if (a != 0.f) {
                    float score = (s_b + a * dm) * inv;
                    float e = __expf(2.f * score);        // fast tanh
                    float attn = 10.f * ((e - 1.f) / (e + 1.f));
                    zloc += __expf(attn);
                    if (score > bscore) { bscore = score; bidx = row; }
                } else {
                    zloc += 1.0f;                          // exp(0)
                }
            }
        }
        av = av_next;
    }
    // wave-wide reduce
#pragma unroll
    for (int m = 32; m >= 1; m >>= 1) zloc += __shfl_xor(zloc, m);
    unsigned long long pk = 0ull;
    if (bidx >= 0)
        pk = ((unsigned long long)fkey(bscore) << 32) |
             (unsigned long long)(0xFFFFFFFFu - (unsigned int)bidx);
#pragma unroll
    for (int m = 32; m >= 1; m >>= 1) {
        unsigned long long o = __shfl_xor(pk, m);
        if (o > pk) pk = o;
    }
    if (lane == 0) { zs[w] = zloc; bs[w] = pk; }
    __syncthreads();
    if (t == 0) {
        float z = zs[0] + zs[1] + zs[2] + zs[3];
        unsigned long long p2 = bs[0];
#pragma unroll
        for (int i = 1; i < 4; ++i) if (bs[i] > p2) p2 = bs[i];
        // publish partials at agent scope (cross-XCD visible), then bump counter
        __hip_atomic_store(&ws->Z_part[blockIdx.x], z,
                           __ATOMIC_RELAXED, __HIP_MEMORY_SCOPE_AGENT);
        __hip_atomic_store(&ws->best_part[blockIdx.x], p2,
                           __ATOMIC_RELAXED, __HIP_MEMORY_SCOPE_AGENT);
        unsigned int prevc = __hip_atomic_fetch_add(&ws->done, 1u,
                           __ATOMIC_ACQ_REL, __HIP_MEMORY_SCOPE_AGENT);
        lastflag = (prevc == GRID - 1) ? 1 : 0;
    }
    __syncthreads();
    if (!lastflag) return;

    // ---- last block: fold all 2048 partials (release sequence on ws->done
    // guarantees every block's agent-scope stores are visible here) ----------
    float z = 0.f;
    unsigned long long pk2 = 0ull;
#pragma unroll
    for (int i = 0; i < GRID / 256; ++i) {
        int s = t + i * 256;
        z += __hip_atomic_load(&ws->Z_part[s],
                               __ATOMIC_RELAXED, __HIP_MEMORY_SCOPE_AGENT);
        unsigned long long o = __hip_atomic_load(&ws->best_part[s],
                               __ATOMIC_RELAXED, __HIP_MEMORY_SCOPE_AGENT);
        if (o > pk2) pk2 = o;
    }
#pragma unroll
    for (int m = 32; m >= 1; m >>= 1) {
        z += __shfl_xor(z, m);
        unsigned long long o = __shfl_xor(pk2, m);
        if (o > pk2) pk2 = o;
    }
    if (lane == 0) { zs[w] = z; bs[w] = pk2; }
    __syncthreads();
    if (t == 0) {
        float Z = zs[0] + zs[1] + zs[2] + zs[3];
        unsigned long long b = bs[0];
#pragma unroll
        for (int i = 1; i < 4; ++i) if (bs[i] > b) b = bs[i];
        unsigned int idx = 0xFFFFFFFFu - (unsigned int)(b & 0xFFFFFFFFu);
        float score = inv_fkey((unsigned int)(b >> 32));
        float p = __expf(10.f * tanhf(score)) / Z;
        if (b == 0ull) { idx = 0; p = 0.f; }
        outp[0] = (float)idx;
        outp[1] = p;
    }
}

extern "C" void kernel_launch(void* const* d_in, const int* in_sizes, int n_in,
                              void* d_out, int out_size, void* d_ws, size_t ws_size,
                              hipStream_t stream) {
    const float* outp = (const float*)d_in[0];
    const float* adj  = (const float*)d_in[1];
    const float* W1   = (const float*)d_in[2];
    const float* b1   = (const float*)d_in[3];
    const float* W2   = (const float*)d_in[4];
    const float* b2   = (const float*)d_in[5];
    const int*   prev = (const int*)d_in[6];
    int n = in_sizes[1];                       // N = 200000
    Ws* ws = (Ws*)d_ws;

    int ntiles = (n + 31) / 32;                // 6250

    prep_kernel<<<PREP_B, 256, 0, stream>>>(outp, W1, b1, W2, b2, prev, ws);
    score_kernel<<<GRID, 256, 0, stream>>>((const float4*)outp, adj, ws,
                                           (float*)d_out, n, ntiles);
}

// Round 2
// 162.742 us; speedup vs baseline: 1.3737x; 1.3737x over previous
//
#include <hip/hip_runtime.h>
#include <math.h>

#define H 128
#define HID 512
#define GRID 2048          // score blocks == partial slots
#define PREP_B 16          // prep blocks == u partial slots

struct Ws {
    float sb_part[PREP_B];
    float u_part[PREP_B][H];
    unsigned long long best_part[GRID];   // 8-aligned
    float Z_part[GRID];
};

__device__ __forceinline__ unsigned int fkey(float f) {
    unsigned int u = __float_as_uint(f);
    return (u & 0x80000000u) ? ~u : (u | 0x80000000u);
}
__device__ __forceinline__ float inv_fkey(unsigned int k) {
    return __uint_as_float((k & 0x80000000u) ? (k ^ 0x80000000u) : ~k);
}

// ---------------- prep: 16 independent blocks, no cross-block deps ------------
__global__ __launch_bounds__(256)
void prep_kernel(const float* __restrict__ outp, const float* __restrict__ W1,
                 const float* __restrict__ b1, const float* __restrict__ W2,
                 const float* __restrict__ b2, const int* __restrict__ prev,
                 Ws* __restrict__ ws) {
    __shared__ float phi1_s[32];
    __shared__ float sb_s[8];
    __shared__ float u_s[2][H];
    int t = threadIdx.x;
    int lane = t & 63;
    int c = lane & 31;
    int g = t >> 5;            // half-wave id 0..7, each owns 4 rows
    int kbase = blockIdx.x * 32;
    const float4* vi = (const float4*)(outp + (size_t)prev[0] * H);
    float4 v = vi[c];
    float sb = 0.f;
#pragma unroll
    for (int r = 0; r < 4; ++r) {
        int kl = g * 4 + r;
        int k = kbase + kl;
        float4 w = ((const float4*)(W1 + (size_t)k * H))[c];
        float d = w.x * v.x + w.y * v.y + w.z * v.z + w.w * v.w;
        d += __shfl_xor(d, 16);
        d += __shfl_xor(d, 8);
        d += __shfl_xor(d, 4);
        d += __shfl_xor(d, 2);
        d += __shfl_xor(d, 1);
        if (c == 0) {
            float phi = d + b1[k];
            phi1_s[kl] = phi;
            sb += phi * b2[k];
        }
    }
    if (c == 0) sb_s[g] = sb;
    __syncthreads();
    int h = t & 127;
    int g2 = t >> 7;           // 0..1
    float up = 0.f;
#pragma unroll
    for (int kk = 0; kk < 16; ++kk) {
        int kl = g2 * 16 + kk;
        up += phi1_s[kl] * W2[(size_t)(kbase + kl) * H + h];
    }
    u_s[g2][h] = up;
    __syncthreads();
    if (t < H) ws->u_part[blockIdx.x][t] = u_s[0][t] + u_s[1][t];
    if (t == 0) {
        float s = 0.f;
#pragma unroll
        for (int i = 0; i < 8; ++i) s += sb_s[i];
        ws->sb_part[blockIdx.x] = s;
    }
}

// ---------------- main streaming pass: adj-gated, software-pipelined ----------
// Wave w owns rows [tile*32 + w*8, +8). Math identical to the verified 167µs
// version. New: depth-1 tile pipeline — adj is prefetched TWO tiles ahead,
// and tile t+1's gates + x-loads are issued BEFORE tile t's compute, so the
// x HBM latency of every steady-state tile hides under the previous tile's
// dot/butterfly/tail work. No global atomics anywhere (round-1 lesson: one
// agent-scope fetch_add per block on a single address cost ~60 µs).
__global__ __launch_bounds__(256)
void score_kernel(const float4* __restrict__ xv, const float* __restrict__ adj,
                  Ws* __restrict__ ws, int n, int ntiles) {
    __shared__ float zs[4];
    __shared__ unsigned long long bs[4];
    const float inv = 0.04419417382415922f;   // 1/sqrt(512)
    int t = threadIdx.x;
    int lane = t & 63;
    int c = lane & 31;
    int hv = lane >> 5;
    int w = t >> 6;
    // fold the 16 u/sb partials (8 KB, L2-hot)
    float4 uv = make_float4(0.f, 0.f, 0.f, 0.f);
    float s_b = 0.f;
#pragma unroll
    for (int b = 0; b < PREP_B; ++b) {
        float4 p = ((const float4*)ws->u_part[b])[c];
        uv.x += p.x; uv.y += p.y; uv.z += p.z; uv.w += p.w;
        s_b += ws->sb_part[b];
    }
    float zloc = 0.f;
    float bscore = -3.4e38f;
    int bidx = -1;

    int t0 = blockIdx.x;
    // ---- prologue: adj(t0), adj(t0+GRID) in flight; gates+x issued for t0 ----
    float av_cur = 0.f, av_nxt = 0.f;
    if (t0 < ntiles) {
        int rb = t0 * 32 + w * 8;
        if (lane < 8 && rb + lane < n) av_cur = adj[rb + lane];
    }
    if (t0 + GRID < ntiles) {
        int rb = (t0 + GRID) * 32 + w * 8;
        if (lane < 8 && rb + lane < n) av_nxt = adj[rb + lane];
    }
    float a4[4];
    float4 x4[4];
#pragma unroll
    for (int r = 0; r < 4; ++r) {
        a4[r] = __shfl(av_cur, hv + 2 * r);
        if (a4[r] != 0.f) {
            int row = t0 * 32 + w * 8 + hv + 2 * r;
            x4[r] = xv[(size_t)row * 32 + c];
        }
    }

    for (int tile = t0; tile < ntiles; tile += GRID) {
        // ---- stage tile+GRID: gates from prefetched adj, issue its x loads,
        //      and prefetch adj two tiles ahead ----
        int tn = tile + GRID;
        float a4n[4];
        float4 x4n[4];
#pragma unroll
        for (int r = 0; r < 4; ++r) {
            a4n[r] = (tn < ntiles) ? __shfl(av_nxt, hv + 2 * r) : 0.f;
            if (a4n[r] != 0.f) {
                int row = tn * 32 + w * 8 + hv + 2 * r;
                x4n[r] = xv[(size_t)row * 32 + c];
            }
        }
        float av_nn = 0.f;
        int tnn = tile + 2 * GRID;
        if (tnn < ntiles) {
            int rb = tnn * 32 + w * 8;
            if (lane < 8 && rb + lane < n) av_nn = adj[rb + lane];
        }
        // ---- compute current tile (x4 loads were issued last iteration) ----
        float d[4];
#pragma unroll
        for (int r = 0; r < 4; ++r) {
            float dd = 0.f;
            if (a4[r] != 0.f)
                dd = x4[r].x * uv.x + x4[r].y * uv.y +
                     x4[r].z * uv.z + x4[r].w * uv.w;
            d[r] = dd;
        }
        // butterfly reductions, only for live rows (xor<=16 stays in half-wave)
#pragma unroll
        for (int r = 0; r < 4; ++r) {
            if (a4[r] != 0.f) {
                float dd = d[r];
                dd += __shfl_xor(dd, 16);
                dd += __shfl_xor(dd, 8);
                dd += __shfl_xor(dd, 4);
                dd += __shfl_xor(dd, 2);
                dd += __shfl_xor(dd, 1);
                d[r] = dd;
            }
        }
        // tail: lanes c<4 own row r=c
        if (c < 4) {
            int row = tile * 32 + w * 8 + hv + 2 * c;
            if (row < n) {
                float a = a4[0];
                float dm = d[0];
#pragma unroll
                for (int r = 1; r < 4; ++r) {
                    a  = (c == r) ? a4[r] : a;
                    dm = (c == r) ? d[r] : dm;
                }
                if (a != 0.f) {
                    float score = (s_b + a * dm) * inv;
                    float e = __expf(2.f * score);        // fast tanh
                    float attn = 10.f * ((e - 1.f) / (e + 1.f));
                    zloc += __expf(attn);
                    if (score > bscore) { bscore = score; bidx = row; }
                } else {
                    zloc += 1.0f;                          // exp(0)
                }
            }
        }
        // ---- rotate pipeline ----
#pragma unroll
        for (int r = 0; r < 4; ++r) { a4[r] = a4n[r]; x4[r] = x4n[r]; }
        av_nxt = av_nn;
    }
    // wave-wide reduce
#pragma unroll
    for (int m = 32; m >= 1; m >>= 1) zloc += __shfl_xor(zloc, m);
    unsigned long long pk = 0ull;
    if (bidx >= 0)
        pk = ((unsigned long long)fkey(bscore) << 32) |
             (unsigned long long)(0xFFFFFFFFu - (unsigned int)bidx);
#pragma unroll
    for (int m = 32; m >= 1; m >>= 1) {
        unsigned long long o = __shfl_xor(pk, m);
        if (o > pk) pk = o;
    }
    if (lane == 0) { zs[w] = zloc; bs[w] = pk; }
    __syncthreads();
    if (t == 0) {
        float z = zs[0] + zs[1] + zs[2] + zs[3];
        unsigned long long p2 = bs[0];
#pragma unroll
        for (int i = 1; i < 4; ++i) if (bs[i] > p2) p2 = bs[i];
        ws->Z_part[blockIdx.x] = z;            // plain stores, own slot
        ws->best_part[blockIdx.x] = p2;
    }
}

// ---------------- reduce: 1 block, 1024 threads -------------------------------
__global__ __launch_bounds__(1024)
void reduce_kernel(const Ws* __restrict__ ws, float* __restrict__ outp) {
    __shared__ float zs[16];
    __shared__ unsigned long long bs[16];
    int t = threadIdx.x;
    int lane = t & 63;
    float z = ws->Z_part[t] + ws->Z_part[t + 1024];
    unsigned long long pk = ws->best_part[t];
    unsigned long long o2 = ws->best_part[t + 1024];
    if (o2 > pk) pk = o2;
#pragma unroll
    for (int m = 32; m >= 1; m >>= 1) {
        z += __shfl_xor(z, m);
        unsigned long long o = __shfl_xor(pk, m);
        if (o > pk) pk = o;
    }
    if (lane == 0) { zs[t >> 6] = z; bs[t >> 6] = pk; }
    __syncthreads();
    if (t == 0) {
        float Z = 0.f;
        unsigned long long b = 0ull;
#pragma unroll
        for (int i = 0; i < 16; ++i) { Z += zs[i]; if (bs[i] > b) b = bs[i]; }
        unsigned int idx = 0xFFFFFFFFu - (unsigned int)(b & 0xFFFFFFFFu);
        float score = inv_fkey((unsigned int)(b >> 32));
        float p = __expf(10.f * tanhf(score)) / Z;
        if (b == 0ull) { idx = 0; p = 0.f; }
        outp[0] = (float)idx;
        outp[1] = p;
    }
}

extern "C" void kernel_launch(void* const* d_in, const int* in_sizes, int n_in,
                              void* d_out, int out_size, void* d_ws, size_t ws_size,
                              hipStream_t stream) {
    const float* outp = (const float*)d_in[0];
    const float* adj  = (const float*)d_in[1];
    const float* W1   = (const float*)d_in[2];
    const float* b1   = (const float*)d_in[3];
    const float* W2   = (const float*)d_in[4];
    const float* b2   = (const float*)d_in[5];
    const int*   prev = (const int*)d_in[6];
    int n = in_sizes[1];                       // N = 200000
    Ws* ws = (Ws*)d_ws;

    int ntiles = (n + 31) / 32;                // 6250

    prep_kernel<<<PREP_B, 256, 0, stream>>>(outp, W1, b1, W2, b2, prev, ws);
    score_kernel<<<GRID, 256, 0, stream>>>((const float4*)outp, adj, ws, n, ntiles);
    reduce_kernel<<<1, 1024, 0, stream>>>(ws, (float*)d_out);
}

// Round 3
// 161.689 us; speedup vs baseline: 1.3827x; 1.0065x over previous
//
#include <hip/hip_runtime.h>
#include <math.h>

#define H 128
#define HID 512
#define GRID 1024          // score blocks == partial slots (6 tiles/block)
#define PREP_B 16          // prep blocks == u partial slots

struct Ws {
    float sb_part[PREP_B];
    float u_part[PREP_B][H];
    unsigned long long best_part[GRID];   // 8-aligned
    float Z_part[GRID];
};

__device__ __forceinline__ unsigned int fkey(float f) {
    unsigned int u = __float_as_uint(f);
    return (u & 0x80000000u) ? ~u : (u | 0x80000000u);
}
__device__ __forceinline__ float inv_fkey(unsigned int k) {
    return __uint_as_float((k & 0x80000000u) ? (k ^ 0x80000000u) : ~k);
}

// ---------------- prep: 16 independent blocks, no cross-block deps ------------
__global__ __launch_bounds__(256)
void prep_kernel(const float* __restrict__ outp, const float* __restrict__ W1,
                 const float* __restrict__ b1, const float* __restrict__ W2,
                 const float* __restrict__ b2, const int* __restrict__ prev,
                 Ws* __restrict__ ws) {
    __shared__ float phi1_s[32];
    __shared__ float sb_s[8];
    __shared__ float u_s[2][H];
    int t = threadIdx.x;
    int lane = t & 63;
    int c = lane & 31;
    int g = t >> 5;            // half-wave id 0..7, each owns 4 rows
    int kbase = blockIdx.x * 32;
    const float4* vi = (const float4*)(outp + (size_t)prev[0] * H);
    float4 v = vi[c];
    float sb = 0.f;
#pragma unroll
    for (int r = 0; r < 4; ++r) {
        int kl = g * 4 + r;
        int k = kbase + kl;
        float4 w = ((const float4*)(W1 + (size_t)k * H))[c];
        float d = w.x * v.x + w.y * v.y + w.z * v.z + w.w * v.w;
        d += __shfl_xor(d, 16);
        d += __shfl_xor(d, 8);
        d += __shfl_xor(d, 4);
        d += __shfl_xor(d, 2);
        d += __shfl_xor(d, 1);
        if (c == 0) {
            float phi = d + b1[k];
            phi1_s[kl] = phi;
            sb += phi * b2[k];
        }
    }
    if (c == 0) sb_s[g] = sb;
    __syncthreads();
    int h = t & 127;
    int g2 = t >> 7;           // 0..1
    float up = 0.f;
#pragma unroll
    for (int kk = 0; kk < 16; ++kk) {
        int kl = g2 * 16 + kk;
        up += phi1_s[kl] * W2[(size_t)(kbase + kl) * H + h];
    }
    u_s[g2][h] = up;
    __syncthreads();
    if (t < H) ws->u_part[blockIdx.x][t] = u_s[0][t] + u_s[1][t];
    if (t == 0) {
        float s = 0.f;
#pragma unroll
        for (int i = 0; i < 8; ++i) s += sb_s[i];
        ws->sb_part[blockIdx.x] = s;
    }
}

// ---------------- main streaming pass: adj-gated, software-pipelined ----------
// Wave w owns rows [tile*32 + w*8, +8). Depth-1 tile pipeline: adj prefetched
// two tiles ahead; tile t+1's gates + x-loads issued before tile t's compute.
// GRID=1024 -> ~6 tiles/block: steady-state amortizes the pipeline prologue
// 2x vs GRID=2048, and halves CP dispatch/drain + partial-slot traffic.
// No global atomics (round-1 lesson: single-address agent-scope fetch_add
// serializes at ~44ns/block = catastrophic).
__global__ __launch_bounds__(256)
void score_kernel(const float4* __restrict__ xv, const float* __restrict__ adj,
                  Ws* __restrict__ ws, int n, int ntiles) {
    __shared__ float zs[4];
    __shared__ unsigned long long bs[4];
    const float inv = 0.04419417382415922f;   // 1/sqrt(512)
    int t = threadIdx.x;
    int lane = t & 63;
    int c = lane & 31;
    int hv = lane >> 5;
    int w = t >> 6;
    // fold the 16 u/sb partials (8 KB, L3-hot broadcast)
    float4 uv = make_float4(0.f, 0.f, 0.f, 0.f);
    float s_b = 0.f;
#pragma unroll
    for (int b = 0; b < PREP_B; ++b) {
        float4 p = ((const float4*)ws->u_part[b])[c];
        uv.x += p.x; uv.y += p.y; uv.z += p.z; uv.w += p.w;
        s_b += ws->sb_part[b];
    }
    float zloc = 0.f;
    float bscore = -3.4e38f;
    int bidx = -1;

    int t0 = blockIdx.x;
    // ---- prologue: adj(t0), adj(t0+GRID) in flight; gates+x issued for t0 ----
    float av_cur = 0.f, av_nxt = 0.f;
    if (t0 < ntiles) {
        int rb = t0 * 32 + w * 8;
        if (lane < 8 && rb + lane < n) av_cur = adj[rb + lane];
    }
    if (t0 + GRID < ntiles) {
        int rb = (t0 + GRID) * 32 + w * 8;
        if (lane < 8 && rb + lane < n) av_nxt = adj[rb + lane];
    }
    float a4[4];
    float4 x4[4];
#pragma unroll
    for (int r = 0; r < 4; ++r) {
        a4[r] = __shfl(av_cur, hv + 2 * r);
        if (a4[r] != 0.f) {
            int row = t0 * 32 + w * 8 + hv + 2 * r;
            x4[r] = xv[(size_t)row * 32 + c];
        }
    }

    for (int tile = t0; tile < ntiles; tile += GRID) {
        // ---- stage tile+GRID: gates from prefetched adj, issue its x loads,
        //      and prefetch adj two tiles ahead ----
        int tn = tile + GRID;
        float a4n[4];
        float4 x4n[4];
#pragma unroll
        for (int r = 0; r < 4; ++r) {
            a4n[r] = (tn < ntiles) ? __shfl(av_nxt, hv + 2 * r) : 0.f;
            if (a4n[r] != 0.f) {
                int row = tn * 32 + w * 8 + hv + 2 * r;
                x4n[r] = xv[(size_t)row * 32 + c];
            }
        }
        float av_nn = 0.f;
        int tnn = tile + 2 * GRID;
        if (tnn < ntiles) {
            int rb = tnn * 32 + w * 8;
            if (lane < 8 && rb + lane < n) av_nn = adj[rb + lane];
        }
        // ---- compute current tile (x4 loads were issued last iteration) ----
        float d[4];
#pragma unroll
        for (int r = 0; r < 4; ++r) {
            float dd = 0.f;
            if (a4[r] != 0.f)
                dd = x4[r].x * uv.x + x4[r].y * uv.y +
                     x4[r].z * uv.z + x4[r].w * uv.w;
            d[r] = dd;
        }
        // butterfly reductions, only for live rows (xor<=16 stays in half-wave)
#pragma unroll
        for (int r = 0; r < 4; ++r) {
            if (a4[r] != 0.f) {
                float dd = d[r];
                dd += __shfl_xor(dd, 16);
                dd += __shfl_xor(dd, 8);
                dd += __shfl_xor(dd, 4);
                dd += __shfl_xor(dd, 2);
                dd += __shfl_xor(dd, 1);
                d[r] = dd;
            }
        }
        // tail: lanes c<4 own row r=c
        if (c < 4) {
            int row = tile * 32 + w * 8 + hv + 2 * c;
            if (row < n) {
                float a = a4[0];
                float dm = d[0];
#pragma unroll
                for (int r = 1; r < 4; ++r) {
                    a  = (c == r) ? a4[r] : a;
                    dm = (c == r) ? d[r] : dm;
                }
                if (a != 0.f) {
                    float score = (s_b + a * dm) * inv;
                    float e = __expf(2.f * score);        // fast tanh
                    float attn = 10.f * ((e - 1.f) / (e + 1.f));
                    zloc += __expf(attn);
                    if (score > bscore) { bscore = score; bidx = row; }
                } else {
                    zloc += 1.0f;                          // exp(0)
                }
            }
        }
        // ---- rotate pipeline ----
#pragma unroll
        for (int r = 0; r < 4; ++r) { a4[r] = a4n[r]; x4[r] = x4n[r]; }
        av_nxt = av_nn;
    }
    // wave-wide reduce
#pragma unroll
    for (int m = 32; m >= 1; m >>= 1) zloc += __shfl_xor(zloc, m);
    unsigned long long pk = 0ull;
    if (bidx >= 0)
        pk = ((unsigned long long)fkey(bscore) << 32) |
             (unsigned long long)(0xFFFFFFFFu - (unsigned int)bidx);
#pragma unroll
    for (int m = 32; m >= 1; m >>= 1) {
        unsigned long long o = __shfl_xor(pk, m);
        if (o > pk) pk = o;
    }
    if (lane == 0) { zs[w] = zloc; bs[w] = pk; }
    __syncthreads();
    if (t == 0) {
        float z = zs[0] + zs[1] + zs[2] + zs[3];
        unsigned long long p2 = bs[0];
#pragma unroll
        for (int i = 1; i < 4; ++i) if (bs[i] > p2) p2 = bs[i];
        ws->Z_part[blockIdx.x] = z;            // plain stores, own slot
        ws->best_part[blockIdx.x] = p2;
    }
}

// ---------------- reduce: 1 block, 1024 threads, 1 partial each ---------------
__global__ __launch_bounds__(1024)
void reduce_kernel(const Ws* __restrict__ ws, float* __restrict__ outp) {
    __shared__ float zs[16];
    __shared__ unsigned long long bs[16];
    int t = threadIdx.x;
    int lane = t & 63;
    float z = ws->Z_part[t];
    unsigned long long pk = ws->best_part[t];
#pragma unroll
    for (int m = 32; m >= 1; m >>= 1) {
        z += __shfl_xor(z, m);
        unsigned long long o = __shfl_xor(pk, m);
        if (o > pk) pk = o;
    }
    if (lane == 0) { zs[t >> 6] = z; bs[t >> 6] = pk; }
    __syncthreads();
    if (t == 0) {
        float Z = 0.f;
        unsigned long long b = 0ull;
#pragma unroll
        for (int i = 0; i < 16; ++i) { Z += zs[i]; if (bs[i] > b) b = bs[i]; }
        unsigned int idx = 0xFFFFFFFFu - (unsigned int)(b & 0xFFFFFFFFu);
        float score = inv_fkey((unsigned int)(b >> 32));
        float p = __expf(10.f * tanhf(score)) / Z;
        if (b == 0ull) { idx = 0; p = 0.f; }
        outp[0] = (float)idx;
        outp[1] = p;
    }
}

extern "C" void kernel_launch(void* const* d_in, const int* in_sizes, int n_in,
                              void* d_out, int out_size, void* d_ws, size_t ws_size,
                              hipStream_t stream) {
    const float* outp = (const float*)d_in[0];
    const float* adj  = (const float*)d_in[1];
    const float* W1   = (const float*)d_in[2];
    const float* b1   = (const float*)d_in[3];
    const float* W2   = (const float*)d_in[4];
    const float* b2   = (const float*)d_in[5];
    const int*   prev = (const int*)d_in[6];
    int n = in_sizes[1];                       // N = 200000
    Ws* ws = (Ws*)d_ws;

    int ntiles = (n + 31) / 32;                // 6250

    prep_kernel<<<PREP_B, 256, 0, stream>>>(outp, W1, b1, W2, b2, prev, ws);
    score_kernel<<<GRID, 256, 0, stream>>>((const float4*)outp, adj, ws, n, ntiles);
    reduce_kernel<<<1, 1024, 0, stream>>>(ws, (float*)d_out);
}